// Round 9
// baseline (1540.902 us; speedup 1.0000x reference)
//
#include <hip/hip_runtime.h>
#include <hip/hip_fp16.h>

#define S_LEN 512
#define BATCH 32
#define CHUNK 16

typedef _Float16 hv2  __attribute__((ext_vector_type(2)));
typedef _Float16 half8 __attribute__((ext_vector_type(8)));
typedef float    f32x4 __attribute__((ext_vector_type(4)));

__device__ __forceinline__ float dot2f(hv2 a, hv2 b, float c) {
#if __has_builtin(__builtin_amdgcn_fdot2)
    return __builtin_amdgcn_fdot2(a, b, c, false);
#else
    return c + (float)a.x * (float)b.x + (float)a.y * (float)b.y;
#endif
}

__device__ __forceinline__ float fast_tanh(float x) {
    float e = __expf(2.f * x);
    return 1.f - 2.f / (e + 1.f);
}

// Step barrier that does NOT drain vmcnt: LDS-only visibility.
__device__ __forceinline__ void lds_barrier() {
    __asm__ volatile("s_waitcnt lgkmcnt(0)\n\ts_barrier" ::: "memory");
}
__device__ __forceinline__ void vm_drain() {
    __asm__ volatile("s_waitcnt vmcnt(0)" ::: "memory");
}

// flags map (128 uints at workspace head):
//  [0..31]   producer progress (t) per batch
//  [64..95]  gemm per-chunk completion count (NGEMM => ready)
#define F_GC0 64

// ---------------------------------------------------------------------------
// Prep: convert to padded f16 (relu fused for emb). Zeroes flags.
// ---------------------------------------------------------------------------
#define E8   1280000   // 32000*320/8
#define W18  64000     // 320*1600/8
#define W28  12800     // 320*320/8
#define FF8  5120      // 128*320/8
#define PREP_TOTAL8 (E8 + W18 + W28 + FF8 + FF8)

__global__ __launch_bounds__(256) void k_prep(
    const float* __restrict__ emb,  const float* __restrict__ Wih1,
    const float* __restrict__ Wih2, const float* __restrict__ fc1w,
    const float* __restrict__ fc2w,
    _Float16* __restrict__ embf, _Float16* __restrict__ Wf1,
    _Float16* __restrict__ Wf2,  _Float16* __restrict__ F1,
    _Float16* __restrict__ F2,   unsigned int* __restrict__ flags)
{
    int gid = blockIdx.x * 256 + threadIdx.x;
    if (gid < 128) flags[gid] = 0u;
    if (gid >= PREP_TOTAL8) return;

    half8 v;
    _Float16* dst;

    if (gid < E8) {
        int row = gid / 40, c8 = (gid - row * 40) * 8;
        #pragma unroll
        for (int j = 0; j < 8; ++j) {
            int c = c8 + j;
            float f = (c < 300) ? emb[(size_t)row * 300 + c] : 0.f;
            v[j] = (_Float16)(f > 0.f ? f : 0.f);
        }
        dst = embf + (size_t)gid * 8;
    } else if (gid < E8 + W18) {
        int i = gid - E8;
        int row = i / 200, c8 = (i - row * 200) * 8;
        #pragma unroll
        for (int j = 0; j < 8; ++j) {
            int c = c8 + j, w = c / 320, cc = c - w * 320;
            float f = (row < 300 && cc < 300) ? Wih1[(size_t)row * 1500 + w * 300 + cc] : 0.f;
            v[j] = (_Float16)f;
        }
        dst = Wf1 + (size_t)i * 8;
    } else if (gid < E8 + W18 + W28) {
        int i = gid - E8 - W18;
        int row = i / 40, c8 = (i - row * 40) * 8;
        #pragma unroll
        for (int j = 0; j < 8; ++j) {
            int c = c8 + j;
            float f = (row < 300 && c < 300) ? Wih2[(size_t)row * 300 + c] : 0.f;
            v[j] = (_Float16)f;
        }
        dst = Wf2 + (size_t)i * 8;
    } else if (gid < E8 + W18 + W28 + FF8) {
        int i = gid - E8 - W18 - W28;
        int row = i / 40, c8 = (i - row * 40) * 8;
        #pragma unroll
        for (int j = 0; j < 8; ++j) {
            int c = c8 + j;
            v[j] = (_Float16)((c < 300) ? fc1w[(size_t)row * 300 + c] : 0.f);
        }
        dst = F1 + (size_t)i * 8;
    } else {
        int i = gid - E8 - W18 - W28 - FF8;
        int row = i / 40, c8 = (i - row * 40) * 8;
        #pragma unroll
        for (int j = 0; j < 8; ++j) {
            int c = c8 + j;
            v[j] = (_Float16)((c < 300) ? fc2w[(size_t)row * 300 + c] : 0.f);
        }
        dst = F2 + (size_t)i * 8;
    }
    *(half8*)dst = v;
}

// ---------------------------------------------------------------------------
// Fused pipeline kernel. 96 blocks x 512 threads, all co-resident.
//  Blocks 0..31  : producer, layer 1 (per-batch) + fused fc1 epilogue.
//  Blocks 32..63 : consumer, layer 2 (per-batch) + fused fc2 epilogue.
//  Blocks 64..95 : GEMM1 persistent chunk-sweep, ONE m-tile per block.
//                  Per chunk: stage the 16x1600 A-tile (embedding gather)
//                  into LDS ONCE (pad stride 1608 f16 -> 2-way conflicts
//                  only), then 8 waves cover all 19 n-tiles from LDS-A and
//                  L2-hot Wf1. A is fetched exactly once (52 MB total) —
//                  fixes R8's 19x A-redundancy (FETCH 195 MB) and halves the
//                  concurrent-CU count (less power-governor drag).
//                  Chunk pace ~2-4us << producer's 19.5us/chunk.
// H2 never touches global memory (fc2 reads the LDS h-ring); EMBF is
// read-only after prep — no alias hazard. MFMA K-order identical to R8
// (kt = w*10+cc) -> bit-identical U1 and absmax.
// ---------------------------------------------------------------------------
#define LDS_BYTES 52096
#define NREC 64
#define NGEMM 32

__device__ __forceinline__ void load_u_regs(float* up, const float* __restrict__ U1,
                                            int b, int t0) {
    #pragma unroll
    for (int j = 0; j < 10; ++j) {
        int e = threadIdx.x + 512 * j;
        int row = e / 300, col = e - row * 300;
        up[j] = (e < 4800) ? U1[((size_t)((t0 + row) * BATCH + b)) * 300 + col] : 0.f;
    }
}

__device__ __forceinline__ void wait_gemm(unsigned int* flags, int c) {
    if (threadIdx.x == 0) {
        while (__hip_atomic_load(&flags[F_GC0 + c], __ATOMIC_ACQUIRE,
                                 __HIP_MEMORY_SCOPE_AGENT) < (unsigned)NGEMM)
            __builtin_amdgcn_s_sleep(2);
    }
    __syncthreads();
}

// Fused FC epilogue: out rows (b*512 + tb + 0..15) x 128 cols from the LDS
// h-ring. Same MFMA layout as the proven k_fc kernel.
__device__ __forceinline__ void fc_epilogue(
    const _Float16 (*hc)[320], const _Float16* __restrict__ F,
    const float* __restrict__ fb, float* __restrict__ out,
    int b, int tb, int wid, int lm, int lq)
{
    f32x4 acc = (f32x4){0.f, 0.f, 0.f, 0.f};
    const int n = wid * 16 + lm;
    const _Float16* frow = F + (size_t)n * 320;
    #pragma unroll
    for (int k0 = 0; k0 < 320; k0 += 32) {
        half8 a  = *(const half8*)&hc[lm][k0 + lq * 8];
        half8 bf = *(const half8*)&frow[k0 + lq * 8];
        acc = __builtin_amdgcn_mfma_f32_16x16x32_f16(a, bf, acc, 0, 0, 0);
    }
    const float bv = fb[n];
    #pragma unroll
    for (int reg = 0; reg < 4; ++reg) {
        const int t = tb + lq * 4 + reg;
        out[(size_t)(b * 512 + t) * 128 + n] = acc[reg] + bv;
    }
}

__global__ __launch_bounds__(512) void k_rec_fused(
    const int* __restrict__ x, const _Float16* __restrict__ embf,
    const _Float16* __restrict__ Wf1,
    const float* __restrict__ bih1, const float* __restrict__ bhh1,
    float* __restrict__ U1, const float* __restrict__ Whh1,
    const _Float16* __restrict__ Wf2, const float* __restrict__ Whh2,
    const float* __restrict__ bih2, const float* __restrict__ bhh2,
    _Float16* __restrict__ H1f,
    const _Float16* __restrict__ F1, const _Float16* __restrict__ F2,
    const float* __restrict__ fb1, const float* __restrict__ fb2,
    float* __restrict__ out1, float* __restrict__ out2,
    unsigned int* __restrict__ flags)
{
    const int tid  = threadIdx.x;
    extern __shared__ char smem[];

    if (blockIdx.x >= NREC) {
        // ============ GEMM1 role: persistent chunk-sweep, LDS-staged A ============
        const int mt   = blockIdx.x - NREC;   // m-tile 0..31 (within each chunk)
        const int wv   = tid >> 6;            // 0..7
        const int lane = tid & 63;
        const int m    = lane & 15;
        const int q    = lane >> 4;
        _Float16 (*Asm)[1608] = (_Float16(*)[1608])smem;   // 16 x 1608 f16 = 51456 B

        for (int c = 0; c < 32; ++c) {
            // stage A-tile: 16 rows x (5 windows x 320) via embedding gather
            #pragma unroll
            for (int e0 = 0; e0 < 7; ++e0) {
                const int e = tid + e0 * 512;
                if (e < 3200) {
                    const int i  = e / 200;
                    const int re = e - i * 200;
                    const int w  = re / 40;
                    const int k8 = re - w * 40;
                    const int r  = c * 512 + mt * 16 + i;
                    const int idx = x[((r & 31) * S_LEN + (r >> 5)) * 5 + w];
                    half8 v = *(const half8*)(embf + (size_t)idx * 320 + k8 * 8);
                    *(half8*)&Asm[i][w * 320 + k8 * 8] = v;
                }
            }
            lds_barrier();

            for (int nt = wv; nt < 19; nt += 8) {
                const int n = nt * 16 + m;
                const _Float16* wrowB = Wf1 + (size_t)n * 1600;
                f32x4 acc = (f32x4){0.f, 0.f, 0.f, 0.f};
                #pragma unroll
                for (int kt = 0; kt < 50; ++kt) {
                    half8 a  = *(const half8*)&Asm[m][kt * 32 + q * 8];
                    half8 bf = *(const half8*)&wrowB[kt * 32 + q * 8];
                    acc = __builtin_amdgcn_mfma_f32_16x16x32_f16(a, bf, acc, 0, 0, 0);
                }
                if (n < 300) {
                    const float bias = bih1[n] + bhh1[n];
                    #pragma unroll
                    for (int reg = 0; reg < 4; ++reg) {
                        const int rr = c * 512 + mt * 16 + q * 4 + reg;
                        U1[(size_t)rr * 300 + n] = acc[reg] + bias;
                    }
                }
            }
            vm_drain();        // own U1 stores complete
            __syncthreads();   // all waves done (also LDS WAR for next stage)
            if (tid == 0)
                __hip_atomic_fetch_add(&flags[F_GC0 + c], 1u,
                                       __ATOMIC_RELEASE, __HIP_MEMORY_SCOPE_AGENT);
        }
        return;
    }

    float   (*partials)[304] = (float(*)[304])smem;
    _Float16 (*hc)[320]      = (_Float16(*)[320])(smem + 12160);
    float   (*uc)[304]       = (float(*)[304])(smem + 22400);
    _Float16 (*h1s)[320]     = (_Float16(*)[320])(smem + 41856);

    const bool comp = tid < 500;
    const int g    = comp ? tid / 50 : 0;
    const int rt   = comp ? tid % 50 : 0;
    const int lane = tid & 63;
    const int wid  = tid >> 6;
    const int lm   = lane & 15;
    const int lq   = lane >> 4;

    // zero h ring (slot 15 = h_{-1} = 0; pad cols stay 0 forever)
    for (int i = tid; i < CHUNK * 320; i += 512)
        ((_Float16*)hc)[i] = (_Float16)0.f;

    if (blockIdx.x < 32) {
        // ========================= producer: layer 1 + fc1 =========================
        const int b = blockIdx.x;
        hv2 w1[6][16];
        if (comp) {
            #pragma unroll
            for (int i = 0; i < 6; ++i) {
                const float* wr = Whh1 + (size_t)(rt + 50 * i) * 300 + g * 32;
                #pragma unroll
                for (int j = 0; j < 16; ++j) {
                    int c0 = g * 32 + 2 * j;
                    hv2 p;
                    p.x = (c0     < 300) ? (_Float16)wr[2 * j]     : (_Float16)0.f;
                    p.y = (c0 + 1 < 300) ? (_Float16)wr[2 * j + 1] : (_Float16)0.f;
                    w1[i][j] = p;
                }
            }
        }

        wait_gemm(flags, 0);
        float upref[10];
        load_u_regs(upref, U1, b, 0);

        for (int c = 0; c < 32; ++c) {
            const int t0 = c * CHUNK;
            if (c > 0) {
                // bulk-store previous chunk's H1 + fused fc1 on the same chunk
                const int tb = t0 - CHUNK;
                for (int i = tid; i < CHUNK * 40; i += 512) {
                    int row = i / 40, c8 = i - row * 40;
                    half8 v = *(const half8*)&hc[row][c8 * 8];
                    *(half8*)&H1f[((size_t)((tb + row) * BATCH + b)) * 320 + c8 * 8] = v;
                }
                fc_epilogue(hc, F1, fb1, out1, b, tb, wid, lm, lq);
            }
            // stage this chunk's U into LDS from prefetch regs
            #pragma unroll
            for (int j = 0; j < 10; ++j) {
                int e = tid + 512 * j;
                if (e < 4800) {
                    int row = e / 300, col = e - row * 300;
                    uc[row][col] = upref[j];
                }
            }
            if (c > 0) {
                vm_drain();       // own H1 stores complete
                __syncthreads();  // all waves' stores complete before release
                if (tid == 0)
                    __hip_atomic_store(&flags[b], (unsigned)t0,
                                       __ATOMIC_RELEASE, __HIP_MEMORY_SCOPE_AGENT);
            }
            if (c + 1 < 32) {
                wait_gemm(flags, c + 1);                 // U1 chunk c+1 ready?
                load_u_regs(upref, U1, b, t0 + CHUNK);   // in flight across steps
            }
            lds_barrier();

            for (int s = 0; s < CHUNK; ++s) {
                if (comp) {
                    const half8* hp = (const half8*)&hc[(s - 1) & 15][g * 32];
                    float a0 = 0.f, a1 = 0.f, a2 = 0.f, a3 = 0.f, a4 = 0.f, a5 = 0.f;
                    #pragma unroll
                    for (int jj = 0; jj < 4; ++jj) {
                        half8 q8 = hp[jj];
                        const hv2* qv = (const hv2*)&q8;
                        #pragma unroll
                        for (int j4 = 0; j4 < 4; ++j4) {
                            const int j = 4 * jj + j4;
                            a0 = dot2f(w1[0][j], qv[j4], a0);
                            a1 = dot2f(w1[1][j], qv[j4], a1);
                            a2 = dot2f(w1[2][j], qv[j4], a2);
                            a3 = dot2f(w1[3][j], qv[j4], a3);
                            a4 = dot2f(w1[4][j], qv[j4], a4);
                            a5 = dot2f(w1[5][j], qv[j4], a5);
                        }
                    }
                    partials[g][rt]       = a0;
                    partials[g][rt + 50]  = a1;
                    partials[g][rt + 100] = a2;
                    partials[g][rt + 150] = a3;
                    partials[g][rt + 200] = a4;
                    partials[g][rt + 250] = a5;
                }
                lds_barrier();
                if (tid < 300) {
                    float ssum = uc[s][tid];
                    #pragma unroll
                    for (int g2 = 0; g2 < 10; ++g2)
                        ssum += partials[g2][tid];
                    hc[s][tid] = (_Float16)fast_tanh(ssum);
                }
                lds_barrier();
            }
        }
        // final chunk: store H1, flag, fused fc1
        {
            const int tb = S_LEN - CHUNK;
            for (int i = tid; i < CHUNK * 40; i += 512) {
                int row = i / 40, c8 = i - row * 40;
                half8 v = *(const half8*)&hc[row][c8 * 8];
                *(half8*)&H1f[((size_t)((tb + row) * BATCH + b)) * 320 + c8 * 8] = v;
            }
            fc_epilogue(hc, F1, fb1, out1, b, tb, wid, lm, lq);
            vm_drain();
            __syncthreads();
            if (tid == 0)
                __hip_atomic_store(&flags[b], (unsigned)S_LEN,
                                   __ATOMIC_RELEASE, __HIP_MEMORY_SCOPE_AGENT);
        }
    } else {
        // ========================= consumer: layer 2 + fc2 =========================
        const int b = blockIdx.x - 32;
        hv2 whh[6][16];
        if (comp) {
            #pragma unroll
            for (int i = 0; i < 6; ++i) {
                const float* wr = Whh2 + (size_t)(rt + 50 * i) * 300 + g * 32;
                #pragma unroll
                for (int j = 0; j < 16; ++j) {
                    int c0 = g * 32 + 2 * j;
                    hv2 p;
                    p.x = (c0     < 300) ? (_Float16)wr[2 * j]     : (_Float16)0.f;
                    p.y = (c0 + 1 < 300) ? (_Float16)wr[2 * j + 1] : (_Float16)0.f;
                    whh[i][j] = p;
                }
            }
        }
        float bias = (tid < 300) ? (bih2[tid] + bhh2[tid]) : 0.f;

        for (int c = 0; c < 32; ++c) {
            const int t0 = c * CHUNK;
            if (c > 0) {
                // fused fc2 on previous chunk's h2 (still in hc ring);
                // runs before the producer poll, so it's hidden under the wait
                fc_epilogue(hc, F2, fb2, out2, b, t0 - CHUNK, wid, lm, lq);
            }
            if (tid == 0) {
                while (__hip_atomic_load(&flags[b], __ATOMIC_ACQUIRE,
                                         __HIP_MEMORY_SCOPE_AGENT) < (unsigned)(t0 + CHUNK))
                    __builtin_amdgcn_s_sleep(2);
            }
            __syncthreads();   // orders after poll

            // stage this chunk's h1 into LDS
            for (int i = tid; i < CHUNK * 40; i += 512) {
                int row = i / 40, c8 = i - row * 40;
                *(half8*)&h1s[row][c8 * 8] =
                    *(const half8*)&H1f[((size_t)((t0 + row) * BATCH + b)) * 320 + c8 * 8];
            }
            lds_barrier();

            // U2-chunk = h1s @ Wf2^T via MFMA (M=16 steps, N=304, K=320)
            for (int nt = wid; nt < 19; nt += 8) {
                f32x4 acc = (f32x4){0.f, 0.f, 0.f, 0.f};
                const int n = nt * 16 + lm;
                const _Float16* wrow = Wf2 + (size_t)n * 320;
                #pragma unroll
                for (int k0 = 0; k0 < 320; k0 += 32) {
                    half8 a  = *(const half8*)&h1s[lm][k0 + lq * 8];
                    half8 bf = *(const half8*)&wrow[k0 + lq * 8];
                    acc = __builtin_amdgcn_mfma_f32_16x16x32_f16(a, bf, acc, 0, 0, 0);
                }
                #pragma unroll
                for (int reg = 0; reg < 4; ++reg)
                    uc[lq * 4 + reg][n] = acc[reg];
            }
            lds_barrier();

            for (int s = 0; s < CHUNK; ++s) {
                if (comp) {
                    const half8* hp = (const half8*)&hc[(s - 1) & 15][g * 32];
                    float a0 = 0.f, a1 = 0.f, a2 = 0.f, a3 = 0.f, a4 = 0.f, a5 = 0.f;
                    #pragma unroll
                    for (int jj = 0; jj < 4; ++jj) {
                        half8 q8 = hp[jj];
                        const hv2* qv = (const hv2*)&q8;
                        #pragma unroll
                        for (int j4 = 0; j4 < 4; ++j4) {
                            const int j = 4 * jj + j4;
                            a0 = dot2f(whh[0][j], qv[j4], a0);
                            a1 = dot2f(whh[1][j], qv[j4], a1);
                            a2 = dot2f(whh[2][j], qv[j4], a2);
                            a3 = dot2f(whh[3][j], qv[j4], a3);
                            a4 = dot2f(whh[4][j], qv[j4], a4);
                            a5 = dot2f(whh[5][j], qv[j4], a5);
                        }
                    }
                    partials[g][rt]       = a0;
                    partials[g][rt + 50]  = a1;
                    partials[g][rt + 100] = a2;
                    partials[g][rt + 150] = a3;
                    partials[g][rt + 200] = a4;
                    partials[g][rt + 250] = a5;
                }
                lds_barrier();
                if (tid < 300) {
                    float ssum = bias + uc[s][tid];
                    #pragma unroll
                    for (int g2 = 0; g2 < 10; ++g2)
                        ssum += partials[g2][tid];
                    hc[s][tid] = (_Float16)fast_tanh(ssum);
                }
                lds_barrier();
            }
        }
        // final chunk: fused fc2 (h2 chunk 31 in hc ring)
        fc_epilogue(hc, F2, fb2, out2, b, S_LEN - CHUNK, wid, lm, lq);
    }
}

extern "C" void kernel_launch(void* const* d_in, const int* in_sizes, int n_in,
                              void* d_out, int out_size, void* d_ws, size_t ws_size,
                              hipStream_t stream) {
    const int*   x     = (const int*)d_in[0];
    const float* emb   = (const float*)d_in[1];
    const float* Wih1  = (const float*)d_in[2];
    const float* Whh1  = (const float*)d_in[3];
    const float* bih1  = (const float*)d_in[4];
    const float* bhh1  = (const float*)d_in[5];
    const float* Wih2  = (const float*)d_in[6];
    const float* Whh2  = (const float*)d_in[7];
    const float* bih2  = (const float*)d_in[8];
    const float* bhh2  = (const float*)d_in[9];
    const float* fc1w  = (const float*)d_in[10];
    const float* fc1b  = (const float*)d_in[11];
    const float* fc2w  = (const float*)d_in[12];
    const float* fc2b  = (const float*)d_in[13];

    float* out1 = (float*)d_out;
    float* out2 = out1 + (size_t)16384 * 128;

    char* w = (char*)d_ws;
    unsigned int* flags = (unsigned int*)w;              //        512
    float*        U1    = (float*)(w + 512);             // 19,660,800
    _Float16*     H1    = (_Float16*)(w + 19661312);     // 10,485,760
    _Float16*     Wf1   = (_Float16*)(w + 30147072);     //  1,024,000
    _Float16*     Wf2   = (_Float16*)(w + 31171072);     //    204,800
    _Float16*     F1    = (_Float16*)(w + 31375872);     //     81,920
    _Float16*     F2    = (_Float16*)(w + 31457792);     //     81,920
    _Float16*     EMBF  = (_Float16*)(w + 31539712);     // 20,480,000 (read-only after prep)

    const int prep_blocks = (PREP_TOTAL8 + 255) / 256;
    k_prep<<<prep_blocks, 256, 0, stream>>>(emb, Wih1, Wih2, fc1w, fc2w,
                                            EMBF, Wf1, Wf2, F1, F2, flags);

    k_rec_fused<<<NREC + NGEMM, 512, LDS_BYTES, stream>>>(
        x, EMBF, Wf1, bih1, bhh1, U1, Whh1, Wf2, Whh2, bih2, bhh2, H1,
        F1, F2, fc1b, fc2b, out1, out2, flags);
}

// Round 10
// 999.375 us; speedup vs baseline: 1.5419x; 1.5419x over previous
//
#include <hip/hip_runtime.h>
#include <hip/hip_fp16.h>

#define S_LEN 512
#define BATCH 32
#define CHUNK 16

typedef _Float16 hv2  __attribute__((ext_vector_type(2)));
typedef _Float16 half8 __attribute__((ext_vector_type(8)));
typedef float    f32x4 __attribute__((ext_vector_type(4)));

__device__ __forceinline__ float dot2f(hv2 a, hv2 b, float c) {
#if __has_builtin(__builtin_amdgcn_fdot2)
    return __builtin_amdgcn_fdot2(a, b, c, false);
#else
    return c + (float)a.x * (float)b.x + (float)a.y * (float)b.y;
#endif
}

__device__ __forceinline__ float fast_tanh(float x) {
    float e = __expf(2.f * x);
    return 1.f - 2.f / (e + 1.f);
}

// Step barrier that does NOT drain vmcnt: LDS-only visibility.
__device__ __forceinline__ void lds_barrier() {
    __asm__ volatile("s_waitcnt lgkmcnt(0)\n\ts_barrier" ::: "memory");
}
__device__ __forceinline__ void vm_drain() {
    __asm__ volatile("s_waitcnt vmcnt(0)" ::: "memory");
}

// flags map (128 uints at workspace head, zeroed via hipMemsetAsync):
//  [0..31]   producer progress (t) per batch
//  [64..95]  gemm per-chunk completion count (NGEMM => ready)
//  [127]     prep-done counter (NBLK => all prep writes visible)
#define F_GC0 64
#define F_PREP 127

#define E8   1280000   // 32000*320/8
#define W18  64000     // 320*1600/8
#define W28  12800     // 320*320/8
#define FF8  5120      // 128*320/8
#define PREP_TOTAL8 (E8 + W18 + W28 + FF8 + FF8)

#define LDS_BYTES 52096
#define NREC 64
#define NGEMM 76
#define NBLK (NREC + NGEMM)

// ---------------------------------------------------------------------------
// Prep slice (grid-stride over all NBLK blocks): convert to padded f16
// (relu fused for emb). Same element mapping as the old k_prep kernel.
// ---------------------------------------------------------------------------
__device__ void prep_slice(
    const float* __restrict__ emb,  const float* __restrict__ Wih1,
    const float* __restrict__ Wih2, const float* __restrict__ fc1w,
    const float* __restrict__ fc2w,
    _Float16* __restrict__ embf, _Float16* __restrict__ Wf1,
    _Float16* __restrict__ Wf2,  _Float16* __restrict__ F1,
    _Float16* __restrict__ F2)
{
    for (int gid = blockIdx.x * 512 + threadIdx.x; gid < PREP_TOTAL8;
         gid += NBLK * 512) {
        half8 v;
        _Float16* dst;
        if (gid < E8) {
            int row = gid / 40, c8 = (gid - row * 40) * 8;
            #pragma unroll
            for (int j = 0; j < 8; ++j) {
                int c = c8 + j;
                float f = (c < 300) ? emb[(size_t)row * 300 + c] : 0.f;
                v[j] = (_Float16)(f > 0.f ? f : 0.f);
            }
            dst = embf + (size_t)gid * 8;
        } else if (gid < E8 + W18) {
            int i = gid - E8;
            int row = i / 200, c8 = (i - row * 200) * 8;
            #pragma unroll
            for (int j = 0; j < 8; ++j) {
                int c = c8 + j, w = c / 320, cc = c - w * 320;
                float f = (row < 300 && cc < 300) ? Wih1[(size_t)row * 1500 + w * 300 + cc] : 0.f;
                v[j] = (_Float16)f;
            }
            dst = Wf1 + (size_t)i * 8;
        } else if (gid < E8 + W18 + W28) {
            int i = gid - E8 - W18;
            int row = i / 40, c8 = (i - row * 40) * 8;
            #pragma unroll
            for (int j = 0; j < 8; ++j) {
                int c = c8 + j;
                float f = (row < 300 && c < 300) ? Wih2[(size_t)row * 300 + c] : 0.f;
                v[j] = (_Float16)f;
            }
            dst = Wf2 + (size_t)i * 8;
        } else if (gid < E8 + W18 + W28 + FF8) {
            int i = gid - E8 - W18 - W28;
            int row = i / 40, c8 = (i - row * 40) * 8;
            #pragma unroll
            for (int j = 0; j < 8; ++j) {
                int c = c8 + j;
                v[j] = (_Float16)((c < 300) ? fc1w[(size_t)row * 300 + c] : 0.f);
            }
            dst = F1 + (size_t)i * 8;
        } else {
            int i = gid - E8 - W18 - W28 - FF8;
            int row = i / 40, c8 = (i - row * 40) * 8;
            #pragma unroll
            for (int j = 0; j < 8; ++j) {
                int c = c8 + j;
                v[j] = (_Float16)((c < 300) ? fc2w[(size_t)row * 300 + c] : 0.f);
            }
            dst = F2 + (size_t)i * 8;
        }
        *(half8*)dst = v;
    }
}

// ---------------------------------------------------------------------------
// Fused pipeline kernel (R8 structure, proven 805us, + merged prep).
// 140 blocks x 512 threads, all co-resident.
//  All blocks : grid-stride prep slice first; publish flags[F_PREP].
//  Blocks 0..31  : producer, layer 1 (per-batch) + fused fc1 epilogue.
//  Blocks 32..63 : consumer, layer 2 (per-batch) + fused fc2 epilogue.
//  Blocks 64..139: GEMM1 persistent chunk-sweep (gated on prep-done):
//                  76 blocks x 8 waves = 608 waves = the 32 m-tiles x 19
//                  n-tiles of one chunk; ONE 16x16 tile per wave (K=1600),
//                  sweeping chunks 0..31 in order (~4-6us/chunk pace <<
//                  producer's 19.5us/chunk). nt = g%19 keeps each block's
//                  B-slice cache-hot. (R9 lesson: pace = per-block-per-chunk
//                  LATENCY; do not consolidate tiles per block.)
// Prep-dependent uses by rec blocks are transitively ordered behind
// wait_gemm via release/acquire chains: F1@c=1 <= wait_gemm(1); Wf2/F2 <=
// flags[b] <= producer's wait_gemm(0) <= gemm's prep-acquire.
// H2 never touches global memory; EMBF is read-only after prep.
// ---------------------------------------------------------------------------
__device__ __forceinline__ void load_u_regs(float* up, const float* __restrict__ U1,
                                            int b, int t0) {
    #pragma unroll
    for (int j = 0; j < 10; ++j) {
        int e = threadIdx.x + 512 * j;
        int row = e / 300, col = e - row * 300;
        up[j] = (e < 4800) ? U1[((size_t)((t0 + row) * BATCH + b)) * 300 + col] : 0.f;
    }
}

__device__ __forceinline__ void wait_gemm(unsigned int* flags, int c) {
    if (threadIdx.x == 0) {
        while (__hip_atomic_load(&flags[F_GC0 + c], __ATOMIC_ACQUIRE,
                                 __HIP_MEMORY_SCOPE_AGENT) < (unsigned)NGEMM)
            __builtin_amdgcn_s_sleep(2);
    }
    __syncthreads();
}

// Fused FC epilogue: out rows (b*512 + tb + 0..15) x 128 cols from the LDS
// h-ring. Same MFMA layout as the proven k_fc kernel.
__device__ __forceinline__ void fc_epilogue(
    const _Float16 (*hc)[320], const _Float16* __restrict__ F,
    const float* __restrict__ fb, float* __restrict__ out,
    int b, int tb, int wid, int lm, int lq)
{
    f32x4 acc = (f32x4){0.f, 0.f, 0.f, 0.f};
    const int n = wid * 16 + lm;
    const _Float16* frow = F + (size_t)n * 320;
    #pragma unroll
    for (int k0 = 0; k0 < 320; k0 += 32) {
        half8 a  = *(const half8*)&hc[lm][k0 + lq * 8];
        half8 bf = *(const half8*)&frow[k0 + lq * 8];
        acc = __builtin_amdgcn_mfma_f32_16x16x32_f16(a, bf, acc, 0, 0, 0);
    }
    const float bv = fb[n];
    #pragma unroll
    for (int reg = 0; reg < 4; ++reg) {
        const int t = tb + lq * 4 + reg;
        out[(size_t)(b * 512 + t) * 128 + n] = acc[reg] + bv;
    }
}

__global__ __launch_bounds__(512) void k_rec_fused(
    const int* __restrict__ x,
    const float* __restrict__ emb, const float* __restrict__ Wih1f32,
    const float* __restrict__ Wih2f32,
    const float* __restrict__ fc1w, const float* __restrict__ fc2w,
    _Float16* __restrict__ embf, _Float16* __restrict__ Wf1w,
    _Float16* __restrict__ Wf2w, _Float16* __restrict__ F1w,
    _Float16* __restrict__ F2w,
    const float* __restrict__ bih1, const float* __restrict__ bhh1,
    float* __restrict__ U1, const float* __restrict__ Whh1,
    const float* __restrict__ Whh2,
    const float* __restrict__ bih2, const float* __restrict__ bhh2,
    _Float16* __restrict__ H1f,
    const float* __restrict__ fb1, const float* __restrict__ fb2,
    float* __restrict__ out1, float* __restrict__ out2,
    unsigned int* __restrict__ flags)
{
    const int tid  = threadIdx.x;

    // ---- merged prep phase (all blocks) ----
    prep_slice(emb, Wih1f32, Wih2f32, fc1w, fc2w, embf, Wf1w, Wf2w, F1w, F2w);
    vm_drain();
    __syncthreads();
    if (tid == 0)
        __hip_atomic_fetch_add(&flags[F_PREP], 1u,
                               __ATOMIC_RELEASE, __HIP_MEMORY_SCOPE_AGENT);

    const _Float16* Wf1 = Wf1w;
    const _Float16* Wf2 = Wf2w;
    const _Float16* F1  = F1w;
    const _Float16* F2  = F2w;

    if (blockIdx.x >= NREC) {
        // ============ GEMM1 role: persistent chunk-sweep (R8, proven) ============
        if (tid == 0) {
            while (__hip_atomic_load(&flags[F_PREP], __ATOMIC_ACQUIRE,
                                     __HIP_MEMORY_SCOPE_AGENT) < (unsigned)NBLK)
                __builtin_amdgcn_s_sleep(2);
        }
        __syncthreads();

        const int g    = blockIdx.x - NREC;   // 0..75
        const int wv   = tid >> 6;            // 0..7
        const int lane = tid & 63;
        const int m    = lane & 15;
        const int q    = lane >> 4;
        const int nt   = g % 19;              // n-tile: B-slice hot across chunks
        const int mtg  = g / 19;              // 0..3
        const int mt   = mtg * 8 + wv;        // m-tile 0..31
        const int n    = nt * 16 + m;         // B row = D col (n<304<320: padded)
        const _Float16* wrowB = Wf1 + (size_t)n * 1600;
        const float bias = (n < 300) ? (bih1[n] + bhh1[n]) : 0.f;

        for (int c = 0; c < 32; ++c) {
            const int r  = c * 512 + mt * 16 + m;          // A row for this lane
            const int xb = ((r & 31) * S_LEN + (r >> 5)) * 5;
            f32x4 acc = (f32x4){0.f, 0.f, 0.f, 0.f};
            #pragma unroll
            for (int w = 0; w < 5; ++w) {
                const int idx = x[xb + w];
                const _Float16* ea = embf + (size_t)idx * 320;
                const _Float16* wb = wrowB + w * 320;
                #pragma unroll
                for (int cc = 0; cc < 10; ++cc) {
                    half8 a  = *(const half8*)(ea + cc * 32 + q * 8);
                    half8 bf = *(const half8*)(wb + cc * 32 + q * 8);
                    acc = __builtin_amdgcn_mfma_f32_16x16x32_f16(a, bf, acc, 0, 0, 0);
                }
            }
            if (n < 300) {
                #pragma unroll
                for (int reg = 0; reg < 4; ++reg) {
                    const int rr = c * 512 + mt * 16 + q * 4 + reg;
                    U1[(size_t)rr * 300 + n] = acc[reg] + bias;
                }
            }
            vm_drain();        // own stores complete
            __syncthreads();   // all 8 waves' stores complete
            if (tid == 0)
                __hip_atomic_fetch_add(&flags[F_GC0 + c], 1u,
                                       __ATOMIC_RELEASE, __HIP_MEMORY_SCOPE_AGENT);
        }
        return;
    }

    extern __shared__ char smem[];
    float   (*partials)[304] = (float(*)[304])smem;
    _Float16 (*hc)[320]      = (_Float16(*)[320])(smem + 12160);
    float   (*uc)[304]       = (float(*)[304])(smem + 22400);
    _Float16 (*h1s)[320]     = (_Float16(*)[320])(smem + 41856);

    const bool comp = tid < 500;
    const int g    = comp ? tid / 50 : 0;
    const int rt   = comp ? tid % 50 : 0;
    const int lane = tid & 63;
    const int wid  = tid >> 6;
    const int lm   = lane & 15;
    const int lq   = lane >> 4;

    // zero h ring (slot 15 = h_{-1} = 0; pad cols stay 0 forever)
    for (int i = tid; i < CHUNK * 320; i += 512)
        ((_Float16*)hc)[i] = (_Float16)0.f;

    if (blockIdx.x < 32) {
        // ========================= producer: layer 1 + fc1 =========================
        const int b = blockIdx.x;
        hv2 w1[6][16];
        if (comp) {
            #pragma unroll
            for (int i = 0; i < 6; ++i) {
                const float* wr = Whh1 + (size_t)(rt + 50 * i) * 300 + g * 32;
                #pragma unroll
                for (int j = 0; j < 16; ++j) {
                    int c0 = g * 32 + 2 * j;
                    hv2 p;
                    p.x = (c0     < 300) ? (_Float16)wr[2 * j]     : (_Float16)0.f;
                    p.y = (c0 + 1 < 300) ? (_Float16)wr[2 * j + 1] : (_Float16)0.f;
                    w1[i][j] = p;
                }
            }
        }

        wait_gemm(flags, 0);
        float upref[10];
        load_u_regs(upref, U1, b, 0);

        for (int c = 0; c < 32; ++c) {
            const int t0 = c * CHUNK;
            if (c > 0) {
                // bulk-store previous chunk's H1 + fused fc1 on the same chunk
                const int tb = t0 - CHUNK;
                for (int i = tid; i < CHUNK * 40; i += 512) {
                    int row = i / 40, c8 = i - row * 40;
                    half8 v = *(const half8*)&hc[row][c8 * 8];
                    *(half8*)&H1f[((size_t)((tb + row) * BATCH + b)) * 320 + c8 * 8] = v;
                }
                fc_epilogue(hc, F1, fb1, out1, b, tb, wid, lm, lq);
            }
            // stage this chunk's U into LDS from prefetch regs
            #pragma unroll
            for (int j = 0; j < 10; ++j) {
                int e = tid + 512 * j;
                if (e < 4800) {
                    int row = e / 300, col = e - row * 300;
                    uc[row][col] = upref[j];
                }
            }
            if (c > 0) {
                vm_drain();       // own H1 stores complete
                __syncthreads();  // all waves' stores complete before release
                if (tid == 0)
                    __hip_atomic_store(&flags[b], (unsigned)t0,
                                       __ATOMIC_RELEASE, __HIP_MEMORY_SCOPE_AGENT);
            }
            if (c + 1 < 32) {
                wait_gemm(flags, c + 1);                 // U1 chunk c+1 ready?
                load_u_regs(upref, U1, b, t0 + CHUNK);   // in flight across steps
            }
            lds_barrier();

            for (int s = 0; s < CHUNK; ++s) {
                if (comp) {
                    const half8* hp = (const half8*)&hc[(s - 1) & 15][g * 32];
                    float a0 = 0.f, a1 = 0.f, a2 = 0.f, a3 = 0.f, a4 = 0.f, a5 = 0.f;
                    #pragma unroll
                    for (int jj = 0; jj < 4; ++jj) {
                        half8 q8 = hp[jj];
                        const hv2* qv = (const hv2*)&q8;
                        #pragma unroll
                        for (int j4 = 0; j4 < 4; ++j4) {
                            const int j = 4 * jj + j4;
                            a0 = dot2f(w1[0][j], qv[j4], a0);
                            a1 = dot2f(w1[1][j], qv[j4], a1);
                            a2 = dot2f(w1[2][j], qv[j4], a2);
                            a3 = dot2f(w1[3][j], qv[j4], a3);
                            a4 = dot2f(w1[4][j], qv[j4], a4);
                            a5 = dot2f(w1[5][j], qv[j4], a5);
                        }
                    }
                    partials[g][rt]       = a0;
                    partials[g][rt + 50]  = a1;
                    partials[g][rt + 100] = a2;
                    partials[g][rt + 150] = a3;
                    partials[g][rt + 200] = a4;
                    partials[g][rt + 250] = a5;
                }
                lds_barrier();
                if (tid < 300) {
                    float ssum = uc[s][tid];
                    #pragma unroll
                    for (int g2 = 0; g2 < 10; ++g2)
                        ssum += partials[g2][tid];
                    hc[s][tid] = (_Float16)fast_tanh(ssum);
                }
                lds_barrier();
            }
        }
        // final chunk: store H1, flag, fused fc1
        {
            const int tb = S_LEN - CHUNK;
            for (int i = tid; i < CHUNK * 40; i += 512) {
                int row = i / 40, c8 = i - row * 40;
                half8 v = *(const half8*)&hc[row][c8 * 8];
                *(half8*)&H1f[((size_t)((tb + row) * BATCH + b)) * 320 + c8 * 8] = v;
            }
            fc_epilogue(hc, F1, fb1, out1, b, tb, wid, lm, lq);
            vm_drain();
            __syncthreads();
            if (tid == 0)
                __hip_atomic_store(&flags[b], (unsigned)S_LEN,
                                   __ATOMIC_RELEASE, __HIP_MEMORY_SCOPE_AGENT);
        }
    } else {
        // ========================= consumer: layer 2 + fc2 =========================
        const int b = blockIdx.x - 32;
        hv2 whh[6][16];
        if (comp) {
            #pragma unroll
            for (int i = 0; i < 6; ++i) {
                const float* wr = Whh2 + (size_t)(rt + 50 * i) * 300 + g * 32;
                #pragma unroll
                for (int j = 0; j < 16; ++j) {
                    int c0 = g * 32 + 2 * j;
                    hv2 p;
                    p.x = (c0     < 300) ? (_Float16)wr[2 * j]     : (_Float16)0.f;
                    p.y = (c0 + 1 < 300) ? (_Float16)wr[2 * j + 1] : (_Float16)0.f;
                    whh[i][j] = p;
                }
            }
        }
        float bias = (tid < 300) ? (bih2[tid] + bhh2[tid]) : 0.f;

        for (int c = 0; c < 32; ++c) {
            const int t0 = c * CHUNK;
            if (c > 0) {
                // fused fc2 on previous chunk's h2 (still in hc ring);
                // runs before the producer poll, so it's hidden under the wait
                fc_epilogue(hc, F2, fb2, out2, b, t0 - CHUNK, wid, lm, lq);
            }
            if (tid == 0) {
                while (__hip_atomic_load(&flags[b], __ATOMIC_ACQUIRE,
                                         __HIP_MEMORY_SCOPE_AGENT) < (unsigned)(t0 + CHUNK))
                    __builtin_amdgcn_s_sleep(2);
            }
            __syncthreads();   // orders after poll

            // stage this chunk's h1 into LDS
            for (int i = tid; i < CHUNK * 40; i += 512) {
                int row = i / 40, c8 = i - row * 40;
                *(half8*)&h1s[row][c8 * 8] =
                    *(const half8*)&H1f[((size_t)((t0 + row) * BATCH + b)) * 320 + c8 * 8];
            }
            lds_barrier();

            // U2-chunk = h1s @ Wf2^T via MFMA (M=16 steps, N=304, K=320)
            for (int nt = wid; nt < 19; nt += 8) {
                f32x4 acc = (f32x4){0.f, 0.f, 0.f, 0.f};
                const int n = nt * 16 + lm;
                const _Float16* wrow = Wf2 + (size_t)n * 320;
                #pragma unroll
                for (int k0 = 0; k0 < 320; k0 += 32) {
                    half8 a  = *(const half8*)&h1s[lm][k0 + lq * 8];
                    half8 bf = *(const half8*)&wrow[k0 + lq * 8];
                    acc = __builtin_amdgcn_mfma_f32_16x16x32_f16(a, bf, acc, 0, 0, 0);
                }
                #pragma unroll
                for (int reg = 0; reg < 4; ++reg)
                    uc[lq * 4 + reg][n] = acc[reg];
            }
            lds_barrier();

            for (int s = 0; s < CHUNK; ++s) {
                if (comp) {
                    const half8* hp = (const half8*)&hc[(s - 1) & 15][g * 32];
                    float a0 = 0.f, a1 = 0.f, a2 = 0.f, a3 = 0.f, a4 = 0.f, a5 = 0.f;
                    #pragma unroll
                    for (int jj = 0; jj < 4; ++jj) {
                        half8 q8 = hp[jj];
                        const hv2* qv = (const hv2*)&q8;
                        #pragma unroll
                        for (int j4 = 0; j4 < 4; ++j4) {
                            const int j = 4 * jj + j4;
                            a0 = dot2f(whh[0][j], qv[j4], a0);
                            a1 = dot2f(whh[1][j], qv[j4], a1);
                            a2 = dot2f(whh[2][j], qv[j4], a2);
                            a3 = dot2f(whh[3][j], qv[j4], a3);
                            a4 = dot2f(whh[4][j], qv[j4], a4);
                            a5 = dot2f(whh[5][j], qv[j4], a5);
                        }
                    }
                    partials[g][rt]       = a0;
                    partials[g][rt + 50]  = a1;
                    partials[g][rt + 100] = a2;
                    partials[g][rt + 150] = a3;
                    partials[g][rt + 200] = a4;
                    partials[g][rt + 250] = a5;
                }
                lds_barrier();
                if (tid < 300) {
                    float ssum = bias + uc[s][tid];
                    #pragma unroll
                    for (int g2 = 0; g2 < 10; ++g2)
                        ssum += partials[g2][tid];
                    hc[s][tid] = (_Float16)fast_tanh(ssum);
                }
                lds_barrier();
            }
        }
        // final chunk: fused fc2 (h2 chunk 31 in hc ring)
        fc_epilogue(hc, F2, fb2, out2, b, S_LEN - CHUNK, wid, lm, lq);
    }
}

extern "C" void kernel_launch(void* const* d_in, const int* in_sizes, int n_in,
                              void* d_out, int out_size, void* d_ws, size_t ws_size,
                              hipStream_t stream) {
    const int*   x     = (const int*)d_in[0];
    const float* emb   = (const float*)d_in[1];
    const float* Wih1  = (const float*)d_in[2];
    const float* Whh1  = (const float*)d_in[3];
    const float* bih1  = (const float*)d_in[4];
    const float* bhh1  = (const float*)d_in[5];
    const float* Wih2  = (const float*)d_in[6];
    const float* Whh2  = (const float*)d_in[7];
    const float* bih2  = (const float*)d_in[8];
    const float* bhh2  = (const float*)d_in[9];
    const float* fc1w  = (const float*)d_in[10];
    const float* fc1b  = (const float*)d_in[11];
    const float* fc2w  = (const float*)d_in[12];
    const float* fc2b  = (const float*)d_in[13];

    float* out1 = (float*)d_out;
    float* out2 = out1 + (size_t)16384 * 128;

    char* w = (char*)d_ws;
    unsigned int* flags = (unsigned int*)w;              //        512
    float*        U1    = (float*)(w + 512);             // 19,660,800
    _Float16*     H1    = (_Float16*)(w + 19661312);     // 10,485,760
    _Float16*     Wf1   = (_Float16*)(w + 30147072);     //  1,024,000
    _Float16*     Wf2   = (_Float16*)(w + 31171072);     //    204,800
    _Float16*     F1    = (_Float16*)(w + 31375872);     //     81,920
    _Float16*     F2    = (_Float16*)(w + 31457792);     //     81,920
    _Float16*     EMBF  = (_Float16*)(w + 31539712);     // 20,480,000 (read-only after prep)

    hipMemsetAsync(flags, 0, 512, stream);

    k_rec_fused<<<NBLK, 512, LDS_BYTES, stream>>>(
        x, emb, Wih1, Wih2, fc1w, fc2w, EMBF, Wf1, Wf2, F1, F2,
        bih1, bhh1, U1, Whh1, Whh2, bih2, bhh2, H1,
        fc1b, fc2b, out1, out2, flags);
}

// Round 11
// 802.607 us; speedup vs baseline: 1.9199x; 1.2452x over previous
//
#include <hip/hip_runtime.h>
#include <hip/hip_fp16.h>

#define S_LEN 512
#define BATCH 32
#define CHUNK 16

typedef _Float16 hv2  __attribute__((ext_vector_type(2)));
typedef _Float16 half8 __attribute__((ext_vector_type(8)));
typedef float    f32x4 __attribute__((ext_vector_type(4)));

__device__ __forceinline__ float dot2f(hv2 a, hv2 b, float c) {
#if __has_builtin(__builtin_amdgcn_fdot2)
    return __builtin_amdgcn_fdot2(a, b, c, false);
#else
    return c + (float)a.x * (float)b.x + (float)a.y * (float)b.y;
#endif
}

__device__ __forceinline__ float fast_tanh(float x) {
    float e = __expf(2.f * x);
    return 1.f - 2.f / (e + 1.f);
}

// Step barrier that does NOT drain vmcnt: LDS-only visibility.
__device__ __forceinline__ void lds_barrier() {
    __asm__ volatile("s_waitcnt lgkmcnt(0)\n\ts_barrier" ::: "memory");
}
__device__ __forceinline__ void vm_drain() {
    __asm__ volatile("s_waitcnt vmcnt(0)" ::: "memory");
}

// flags map (128 uints at workspace head):
//  [0..31]   producer progress (t) per batch   (flags[0] doubles as the
//            gemm pacing reference — producer 0's progress)
//  [64..95]  gemm per-chunk completion count (NGEMM => ready)
#define F_GC0 64

// ---------------------------------------------------------------------------
// Prep: convert to padded f16 (relu fused for emb). Zeroes flags.
// Emb bulk groups (g8<37) take an unguarded path -> vector loads.
// ---------------------------------------------------------------------------
#define E8   1280000   // 32000*320/8
#define W18  64000     // 320*1600/8
#define W28  12800     // 320*320/8
#define FF8  5120      // 128*320/8
#define PREP_TOTAL8 (E8 + W18 + W28 + FF8 + FF8)

__global__ __launch_bounds__(256) void k_prep(
    const float* __restrict__ emb,  const float* __restrict__ Wih1,
    const float* __restrict__ Wih2, const float* __restrict__ fc1w,
    const float* __restrict__ fc2w,
    _Float16* __restrict__ embf, _Float16* __restrict__ Wf1,
    _Float16* __restrict__ Wf2,  _Float16* __restrict__ F1,
    _Float16* __restrict__ F2,   unsigned int* __restrict__ flags)
{
    int gid = blockIdx.x * 256 + threadIdx.x;
    if (gid < 128) flags[gid] = 0u;
    if (gid >= PREP_TOTAL8) return;

    half8 v;
    _Float16* dst;

    if (gid < E8) {
        int row = gid / 40, g8 = gid - row * 40, c8 = g8 * 8;
        if (g8 < 37) {                       // full 8 elems in-range -> vector loads
            const float* ep = emb + (size_t)row * 300 + c8;
            #pragma unroll
            for (int j = 0; j < 8; ++j) {
                float f = ep[j];
                v[j] = (_Float16)(f > 0.f ? f : 0.f);
            }
        } else {
            #pragma unroll
            for (int j = 0; j < 8; ++j) {
                int c = c8 + j;
                float f = (c < 300) ? emb[(size_t)row * 300 + c] : 0.f;
                v[j] = (_Float16)(f > 0.f ? f : 0.f);
            }
        }
        dst = embf + (size_t)gid * 8;
    } else if (gid < E8 + W18) {
        int i = gid - E8;
        int row = i / 200, c8 = (i - row * 200) * 8;
        #pragma unroll
        for (int j = 0; j < 8; ++j) {
            int c = c8 + j, w = c / 320, cc = c - w * 320;
            float f = (row < 300 && cc < 300) ? Wih1[(size_t)row * 1500 + w * 300 + cc] : 0.f;
            v[j] = (_Float16)f;
        }
        dst = Wf1 + (size_t)i * 8;
    } else if (gid < E8 + W18 + W28) {
        int i = gid - E8 - W18;
        int row = i / 40, c8 = (i - row * 40) * 8;
        #pragma unroll
        for (int j = 0; j < 8; ++j) {
            int c = c8 + j;
            float f = (row < 300 && c < 300) ? Wih2[(size_t)row * 300 + c] : 0.f;
            v[j] = (_Float16)f;
        }
        dst = Wf2 + (size_t)i * 8;
    } else if (gid < E8 + W18 + W28 + FF8) {
        int i = gid - E8 - W18 - W28;
        int row = i / 40, c8 = (i - row * 40) * 8;
        #pragma unroll
        for (int j = 0; j < 8; ++j) {
            int c = c8 + j;
            v[j] = (_Float16)((c < 300) ? fc1w[(size_t)row * 300 + c] : 0.f);
        }
        dst = F1 + (size_t)i * 8;
    } else {
        int i = gid - E8 - W18 - W28 - FF8;
        int row = i / 40, c8 = (i - row * 40) * 8;
        #pragma unroll
        for (int j = 0; j < 8; ++j) {
            int c = c8 + j;
            v[j] = (_Float16)((c < 300) ? fc2w[(size_t)row * 300 + c] : 0.f);
        }
        dst = F2 + (size_t)i * 8;
    }
    *(half8*)dst = v;
}

// ---------------------------------------------------------------------------
// Fused pipeline kernel (R8 structure, best measured 805us, + paced gemm).
// 140 blocks x 512 threads, all co-resident.
//  Blocks 0..31  : producer, layer 1 (per-batch) + fused fc1 epilogue.
//  Blocks 32..63 : consumer, layer 2 (per-batch) + fused fc2 epilogue.
//  Blocks 64..139: GEMM1 persistent chunk-sweep; 76 blocks x 8 waves = 608
//                  waves = the 32 m-tiles x 19 n-tiles of one chunk; ONE
//                  16x16 tile per wave (K=1600), sweeping chunks 0..31.
//                  NEW: chunk c (c>=4) is PACED on producer-0 progress
//                  (flags[0] >= (c-3)*16), so the gemm's 195 MB gather burst
//                  spreads over the whole run (~20% duty cycle, ~4x lower
//                  instantaneous BW, fewer hot CUs -> less governor drag)
//                  while staying 3 chunks ahead of every consumer of U1.
//                  Deadlock-free: producer 0 publishes flags[0]=k*16 BEFORE
//                  its wait_gemm(k+1); chunk k+1's gate needs (k-2)*16.
// H2 never touches global memory (fc2 reads the LDS h-ring); EMBF is
// read-only after prep — no alias hazard.
// ---------------------------------------------------------------------------
#define LDS_BYTES 52096
#define NREC 64
#define NGEMM 76

__device__ __forceinline__ void load_u_regs(float* up, const float* __restrict__ U1,
                                            int b, int t0) {
    #pragma unroll
    for (int j = 0; j < 10; ++j) {
        int e = threadIdx.x + 512 * j;
        int row = e / 300, col = e - row * 300;
        up[j] = (e < 4800) ? U1[((size_t)((t0 + row) * BATCH + b)) * 300 + col] : 0.f;
    }
}

__device__ __forceinline__ void wait_gemm(unsigned int* flags, int c) {
    if (threadIdx.x == 0) {
        while (__hip_atomic_load(&flags[F_GC0 + c], __ATOMIC_ACQUIRE,
                                 __HIP_MEMORY_SCOPE_AGENT) < (unsigned)NGEMM)
            __builtin_amdgcn_s_sleep(2);
    }
    __syncthreads();
}

// Fused FC epilogue: out rows (b*512 + tb + 0..15) x 128 cols from the LDS
// h-ring. Same MFMA layout as the proven k_fc kernel.
__device__ __forceinline__ void fc_epilogue(
    const _Float16 (*hc)[320], const _Float16* __restrict__ F,
    const float* __restrict__ fb, float* __restrict__ out,
    int b, int tb, int wid, int lm, int lq)
{
    f32x4 acc = (f32x4){0.f, 0.f, 0.f, 0.f};
    const int n = wid * 16 + lm;
    const _Float16* frow = F + (size_t)n * 320;
    #pragma unroll
    for (int k0 = 0; k0 < 320; k0 += 32) {
        half8 a  = *(const half8*)&hc[lm][k0 + lq * 8];
        half8 bf = *(const half8*)&frow[k0 + lq * 8];
        acc = __builtin_amdgcn_mfma_f32_16x16x32_f16(a, bf, acc, 0, 0, 0);
    }
    const float bv = fb[n];
    #pragma unroll
    for (int reg = 0; reg < 4; ++reg) {
        const int t = tb + lq * 4 + reg;
        out[(size_t)(b * 512 + t) * 128 + n] = acc[reg] + bv;
    }
}

__global__ __launch_bounds__(512) void k_rec_fused(
    const int* __restrict__ x, const _Float16* __restrict__ embf,
    const _Float16* __restrict__ Wf1,
    const float* __restrict__ bih1, const float* __restrict__ bhh1,
    float* __restrict__ U1, const float* __restrict__ Whh1,
    const _Float16* __restrict__ Wf2, const float* __restrict__ Whh2,
    const float* __restrict__ bih2, const float* __restrict__ bhh2,
    _Float16* __restrict__ H1f,
    const _Float16* __restrict__ F1, const _Float16* __restrict__ F2,
    const float* __restrict__ fb1, const float* __restrict__ fb2,
    float* __restrict__ out1, float* __restrict__ out2,
    unsigned int* __restrict__ flags)
{
    const int tid  = threadIdx.x;

    if (blockIdx.x >= NREC) {
        // ============ GEMM1 role: paced persistent chunk-sweep ============
        const int g    = blockIdx.x - NREC;   // 0..75
        const int wv   = tid >> 6;            // 0..7
        const int lane = tid & 63;
        const int m    = lane & 15;
        const int q    = lane >> 4;
        const int nt   = g % 19;              // n-tile: B-slice hot across chunks
        const int mtg  = g / 19;              // 0..3
        const int mt   = mtg * 8 + wv;        // m-tile 0..31
        const int n    = nt * 16 + m;         // B row = D col (n<304<320: padded)
        const _Float16* wrowB = Wf1 + (size_t)n * 1600;
        const float bias = (n < 300) ? (bih1[n] + bhh1[n]) : 0.f;

        for (int c = 0; c < 32; ++c) {
            if (c >= 4) {                     // pace to producer 0 (3 chunks ahead)
                if (tid == 0) {
                    while (__hip_atomic_load(&flags[0], __ATOMIC_ACQUIRE,
                                             __HIP_MEMORY_SCOPE_AGENT) <
                           (unsigned)((c - 3) * CHUNK))
                        __builtin_amdgcn_s_sleep(4);
                }
                __syncthreads();
            }
            const int r  = c * 512 + mt * 16 + m;          // A row for this lane
            const int xb = ((r & 31) * S_LEN + (r >> 5)) * 5;
            f32x4 acc = (f32x4){0.f, 0.f, 0.f, 0.f};
            #pragma unroll
            for (int w = 0; w < 5; ++w) {
                const int idx = x[xb + w];
                const _Float16* ea = embf + (size_t)idx * 320;
                const _Float16* wb = wrowB + w * 320;
                #pragma unroll
                for (int cc = 0; cc < 10; ++cc) {
                    half8 a  = *(const half8*)(ea + cc * 32 + q * 8);
                    half8 bf = *(const half8*)(wb + cc * 32 + q * 8);
                    acc = __builtin_amdgcn_mfma_f32_16x16x32_f16(a, bf, acc, 0, 0, 0);
                }
            }
            if (n < 300) {
                #pragma unroll
                for (int reg = 0; reg < 4; ++reg) {
                    const int rr = c * 512 + mt * 16 + q * 4 + reg;
                    U1[(size_t)rr * 300 + n] = acc[reg] + bias;
                }
            }
            vm_drain();        // own stores complete
            __syncthreads();   // all 8 waves' stores complete
            if (tid == 0)
                __hip_atomic_fetch_add(&flags[F_GC0 + c], 1u,
                                       __ATOMIC_RELEASE, __HIP_MEMORY_SCOPE_AGENT);
        }
        return;
    }

    extern __shared__ char smem[];
    float   (*partials)[304] = (float(*)[304])smem;
    _Float16 (*hc)[320]      = (_Float16(*)[320])(smem + 12160);
    float   (*uc)[304]       = (float(*)[304])(smem + 22400);
    _Float16 (*h1s)[320]     = (_Float16(*)[320])(smem + 41856);

    const bool comp = tid < 500;
    const int g    = comp ? tid / 50 : 0;
    const int rt   = comp ? tid % 50 : 0;
    const int lane = tid & 63;
    const int wid  = tid >> 6;
    const int lm   = lane & 15;
    const int lq   = lane >> 4;

    // zero h ring (slot 15 = h_{-1} = 0; pad cols stay 0 forever)
    for (int i = tid; i < CHUNK * 320; i += 512)
        ((_Float16*)hc)[i] = (_Float16)0.f;

    if (blockIdx.x < 32) {
        // ========================= producer: layer 1 + fc1 =========================
        const int b = blockIdx.x;
        hv2 w1[6][16];
        if (comp) {
            #pragma unroll
            for (int i = 0; i < 6; ++i) {
                const float* wr = Whh1 + (size_t)(rt + 50 * i) * 300 + g * 32;
                #pragma unroll
                for (int j = 0; j < 16; ++j) {
                    int c0 = g * 32 + 2 * j;
                    hv2 p;
                    p.x = (c0     < 300) ? (_Float16)wr[2 * j]     : (_Float16)0.f;
                    p.y = (c0 + 1 < 300) ? (_Float16)wr[2 * j + 1] : (_Float16)0.f;
                    w1[i][j] = p;
                }
            }
        }

        wait_gemm(flags, 0);
        float upref[10];
        load_u_regs(upref, U1, b, 0);

        for (int c = 0; c < 32; ++c) {
            const int t0 = c * CHUNK;
            if (c > 0) {
                // bulk-store previous chunk's H1 + fused fc1 on the same chunk
                const int tb = t0 - CHUNK;
                for (int i = tid; i < CHUNK * 40; i += 512) {
                    int row = i / 40, c8 = i - row * 40;
                    half8 v = *(const half8*)&hc[row][c8 * 8];
                    *(half8*)&H1f[((size_t)((tb + row) * BATCH + b)) * 320 + c8 * 8] = v;
                }
                fc_epilogue(hc, F1, fb1, out1, b, tb, wid, lm, lq);
            }
            // stage this chunk's U into LDS from prefetch regs
            #pragma unroll
            for (int j = 0; j < 10; ++j) {
                int e = tid + 512 * j;
                if (e < 4800) {
                    int row = e / 300, col = e - row * 300;
                    uc[row][col] = upref[j];
                }
            }
            if (c > 0) {
                vm_drain();       // own H1 stores complete
                __syncthreads();  // all waves' stores complete before release
                if (tid == 0)
                    __hip_atomic_store(&flags[b], (unsigned)t0,
                                       __ATOMIC_RELEASE, __HIP_MEMORY_SCOPE_AGENT);
            }
            if (c + 1 < 32) {
                wait_gemm(flags, c + 1);                 // U1 chunk c+1 ready?
                load_u_regs(upref, U1, b, t0 + CHUNK);   // in flight across steps
            }
            lds_barrier();

            for (int s = 0; s < CHUNK; ++s) {
                if (comp) {
                    const half8* hp = (const half8*)&hc[(s - 1) & 15][g * 32];
                    float a0 = 0.f, a1 = 0.f, a2 = 0.f, a3 = 0.f, a4 = 0.f, a5 = 0.f;
                    #pragma unroll
                    for (int jj = 0; jj < 4; ++jj) {
                        half8 q8 = hp[jj];
                        const hv2* qv = (const hv2*)&q8;
                        #pragma unroll
                        for (int j4 = 0; j4 < 4; ++j4) {
                            const int j = 4 * jj + j4;
                            a0 = dot2f(w1[0][j], qv[j4], a0);
                            a1 = dot2f(w1[1][j], qv[j4], a1);
                            a2 = dot2f(w1[2][j], qv[j4], a2);
                            a3 = dot2f(w1[3][j], qv[j4], a3);
                            a4 = dot2f(w1[4][j], qv[j4], a4);
                            a5 = dot2f(w1[5][j], qv[j4], a5);
                        }
                    }
                    partials[g][rt]       = a0;
                    partials[g][rt + 50]  = a1;
                    partials[g][rt + 100] = a2;
                    partials[g][rt + 150] = a3;
                    partials[g][rt + 200] = a4;
                    partials[g][rt + 250] = a5;
                }
                lds_barrier();
                if (tid < 300) {
                    float ssum = uc[s][tid];
                    #pragma unroll
                    for (int g2 = 0; g2 < 10; ++g2)
                        ssum += partials[g2][tid];
                    hc[s][tid] = (_Float16)fast_tanh(ssum);
                }
                lds_barrier();
            }
        }
        // final chunk: store H1, flag, fused fc1
        {
            const int tb = S_LEN - CHUNK;
            for (int i = tid; i < CHUNK * 40; i += 512) {
                int row = i / 40, c8 = i - row * 40;
                half8 v = *(const half8*)&hc[row][c8 * 8];
                *(half8*)&H1f[((size_t)((tb + row) * BATCH + b)) * 320 + c8 * 8] = v;
            }
            fc_epilogue(hc, F1, fb1, out1, b, tb, wid, lm, lq);
            vm_drain();
            __syncthreads();
            if (tid == 0)
                __hip_atomic_store(&flags[b], (unsigned)S_LEN,
                                   __ATOMIC_RELEASE, __HIP_MEMORY_SCOPE_AGENT);
        }
    } else {
        // ========================= consumer: layer 2 + fc2 =========================
        const int b = blockIdx.x - 32;
        hv2 whh[6][16];
        if (comp) {
            #pragma unroll
            for (int i = 0; i < 6; ++i) {
                const float* wr = Whh2 + (size_t)(rt + 50 * i) * 300 + g * 32;
                #pragma unroll
                for (int j = 0; j < 16; ++j) {
                    int c0 = g * 32 + 2 * j;
                    hv2 p;
                    p.x = (c0     < 300) ? (_Float16)wr[2 * j]     : (_Float16)0.f;
                    p.y = (c0 + 1 < 300) ? (_Float16)wr[2 * j + 1] : (_Float16)0.f;
                    whh[i][j] = p;
                }
            }
        }
        float bias = (tid < 300) ? (bih2[tid] + bhh2[tid]) : 0.f;

        for (int c = 0; c < 32; ++c) {
            const int t0 = c * CHUNK;
            if (c > 0) {
                // fused fc2 on previous chunk's h2 (still in hc ring);
                // runs before the producer poll, so it's hidden under the wait
                fc_epilogue(hc, F2, fb2, out2, b, t0 - CHUNK, wid, lm, lq);
            }
            if (tid == 0) {
                while (__hip_atomic_load(&flags[b], __ATOMIC_ACQUIRE,
                                         __HIP_MEMORY_SCOPE_AGENT) < (unsigned)(t0 + CHUNK))
                    __builtin_amdgcn_s_sleep(2);
            }
            __syncthreads();   // orders after poll

            // stage this chunk's h1 into LDS
            for (int i = tid; i < CHUNK * 40; i += 512) {
                int row = i / 40, c8 = i - row * 40;
                *(half8*)&h1s[row][c8 * 8] =
                    *(const half8*)&H1f[((size_t)((t0 + row) * BATCH + b)) * 320 + c8 * 8];
            }
            lds_barrier();

            // U2-chunk = h1s @ Wf2^T via MFMA (M=16 steps, N=304, K=320)
            for (int nt = wid; nt < 19; nt += 8) {
                f32x4 acc = (f32x4){0.f, 0.f, 0.f, 0.f};
                const int n = nt * 16 + lm;
                const _Float16* wrow = Wf2 + (size_t)n * 320;
                #pragma unroll
                for (int k0 = 0; k0 < 320; k0 += 32) {
                    half8 a  = *(const half8*)&h1s[lm][k0 + lq * 8];
                    half8 bf = *(const half8*)&wrow[k0 + lq * 8];
                    acc = __builtin_amdgcn_mfma_f32_16x16x32_f16(a, bf, acc, 0, 0, 0);
                }
                #pragma unroll
                for (int reg = 0; reg < 4; ++reg)
                    uc[lq * 4 + reg][n] = acc[reg];
            }
            lds_barrier();

            for (int s = 0; s < CHUNK; ++s) {
                if (comp) {
                    const half8* hp = (const half8*)&hc[(s - 1) & 15][g * 32];
                    float a0 = 0.f, a1 = 0.f, a2 = 0.f, a3 = 0.f, a4 = 0.f, a5 = 0.f;
                    #pragma unroll
                    for (int jj = 0; jj < 4; ++jj) {
                        half8 q8 = hp[jj];
                        const hv2* qv = (const hv2*)&q8;
                        #pragma unroll
                        for (int j4 = 0; j4 < 4; ++j4) {
                            const int j = 4 * jj + j4;
                            a0 = dot2f(whh[0][j], qv[j4], a0);
                            a1 = dot2f(whh[1][j], qv[j4], a1);
                            a2 = dot2f(whh[2][j], qv[j4], a2);
                            a3 = dot2f(whh[3][j], qv[j4], a3);
                            a4 = dot2f(whh[4][j], qv[j4], a4);
                            a5 = dot2f(whh[5][j], qv[j4], a5);
                        }
                    }
                    partials[g][rt]       = a0;
                    partials[g][rt + 50]  = a1;
                    partials[g][rt + 100] = a2;
                    partials[g][rt + 150] = a3;
                    partials[g][rt + 200] = a4;
                    partials[g][rt + 250] = a5;
                }
                lds_barrier();
                if (tid < 300) {
                    float ssum = bias + uc[s][tid];
                    #pragma unroll
                    for (int g2 = 0; g2 < 10; ++g2)
                        ssum += partials[g2][tid];
                    hc[s][tid] = (_Float16)fast_tanh(ssum);
                }
                lds_barrier();
            }
        }
        // final chunk: fused fc2 (h2 chunk 31 in hc ring)
        fc_epilogue(hc, F2, fb2, out2, b, S_LEN - CHUNK, wid, lm, lq);
    }
}

extern "C" void kernel_launch(void* const* d_in, const int* in_sizes, int n_in,
                              void* d_out, int out_size, void* d_ws, size_t ws_size,
                              hipStream_t stream) {
    const int*   x     = (const int*)d_in[0];
    const float* emb   = (const float*)d_in[1];
    const float* Wih1  = (const float*)d_in[2];
    const float* Whh1  = (const float*)d_in[3];
    const float* bih1  = (const float*)d_in[4];
    const float* bhh1  = (const float*)d_in[5];
    const float* Wih2  = (const float*)d_in[6];
    const float* Whh2  = (const float*)d_in[7];
    const float* bih2  = (const float*)d_in[8];
    const float* bhh2  = (const float*)d_in[9];
    const float* fc1w  = (const float*)d_in[10];
    const float* fc1b  = (const float*)d_in[11];
    const float* fc2w  = (const float*)d_in[12];
    const float* fc2b  = (const float*)d_in[13];

    float* out1 = (float*)d_out;
    float* out2 = out1 + (size_t)16384 * 128;

    char* w = (char*)d_ws;
    unsigned int* flags = (unsigned int*)w;              //        512
    float*        U1    = (float*)(w + 512);             // 19,660,800
    _Float16*     H1    = (_Float16*)(w + 19661312);     // 10,485,760
    _Float16*     Wf1   = (_Float16*)(w + 30147072);     //  1,024,000
    _Float16*     Wf2   = (_Float16*)(w + 31171072);     //    204,800
    _Float16*     F1    = (_Float16*)(w + 31375872);     //     81,920
    _Float16*     F2    = (_Float16*)(w + 31457792);     //     81,920
    _Float16*     EMBF  = (_Float16*)(w + 31539712);     // 20,480,000 (read-only after prep)

    const int prep_blocks = (PREP_TOTAL8 + 255) / 256;
    k_prep<<<prep_blocks, 256, 0, stream>>>(emb, Wih1, Wih2, fc1w, fc2w,
                                            EMBF, Wf1, Wf2, F1, F2, flags);

    k_rec_fused<<<NREC + NGEMM, 512, LDS_BYTES, stream>>>(
        x, EMBF, Wf1, bih1, bhh1, U1, Whh1, Wf2, Whh2, bih2, bhh2, H1,
        F1, F2, fc1b, fc2b, out1, out2, flags);
}